// Round 1
// baseline (464.465 us; speedup 1.0000x reference)
//
#include <hip/hip_runtime.h>

// ---------------------------------------------------------------------------
// Debiased Representation Loss — fused MI355X implementation.
// B=4096 samples, D=768 feat, HID=256, 200 classes (100 old + 100 new).
// Heavy part: three pairwise 4096x4096 matrices (base_sim mask K=768,
// sim K=768, attn K=256) fused flash-style; per-row state is only
// (l, a, denom, nn) because attn logits are small enough to skip online max.
// ---------------------------------------------------------------------------

#define B_N   4096
#define D_N   768
#define HID_N 256
#define NCLS  200

typedef __attribute__((ext_vector_type(8))) short v8s;   // 8 x bf16 (4 VGPRs)
typedef __attribute__((ext_vector_type(4))) float v4f;   // MFMA accumulator

// round-to-nearest-even fp32 -> bf16
__device__ __forceinline__ unsigned short f2bf(float x) {
    unsigned int u = __float_as_uint(x);
    unsigned int r = (u + 0x7FFFu + ((u >> 16) & 1u)) >> 16;
    return (unsigned short)r;
}

// ---------------------------------------------------------------------------
// Kernel 1: L2-normalize z_u and base_features rows; emit bf16 copies.
// one block per row; 768 = 256 threads x 3 elements
// ---------------------------------------------------------------------------
__global__ __launch_bounds__(256) void normalize_k(
    const float* __restrict__ z, const float* __restrict__ base,
    unsigned short* __restrict__ zn, unsigned short* __restrict__ bn,
    unsigned short* __restrict__ zb)
{
    int row = blockIdx.x, tid = threadIdx.x;
    __shared__ float ws1[4], ws2[4];
    const float* zr = z    + (size_t)row * D_N;
    const float* br = base + (size_t)row * D_N;
    float z0 = zr[tid], z1 = zr[tid + 256], z2 = zr[tid + 512];
    float b0 = br[tid], b1 = br[tid + 256], b2 = br[tid + 512];
    float s1 = z0*z0 + z1*z1 + z2*z2;
    float s2 = b0*b0 + b1*b1 + b2*b2;
    #pragma unroll
    for (int m = 32; m > 0; m >>= 1) { s1 += __shfl_xor(s1, m); s2 += __shfl_xor(s2, m); }
    if ((tid & 63) == 0) { ws1[tid >> 6] = s1; ws2[tid >> 6] = s2; }
    __syncthreads();
    float t1 = ws1[0] + ws1[1] + ws1[2] + ws1[3];
    float t2 = ws2[0] + ws2[1] + ws2[2] + ws2[3];
    float sc1 = 1.0f / fmaxf(sqrtf(t1), 1e-12f);
    float sc2 = 1.0f / fmaxf(sqrtf(t2), 1e-12f);
    size_t o = (size_t)row * D_N;
    zn[o+tid] = f2bf(z0*sc1); zn[o+tid+256] = f2bf(z1*sc1); zn[o+tid+512] = f2bf(z2*sc1);
    bn[o+tid] = f2bf(b0*sc2); bn[o+tid+256] = f2bf(b1*sc2); bn[o+tid+512] = f2bf(b2*sc2);
    zb[o+tid] = f2bf(z0);     zb[o+tid+256] = f2bf(z1);     zb[o+tid+512] = f2bf(z2);
}

// ---------------------------------------------------------------------------
// Kernel 2: convert f1_w / f2_w to bf16
// ---------------------------------------------------------------------------
__global__ __launch_bounds__(256) void convert_w(
    const float* __restrict__ w1, const float* __restrict__ w2,
    unsigned short* __restrict__ o1, unsigned short* __restrict__ o2)
{
    int i = blockIdx.x * 256 + threadIdx.x;
    if (i < HID_N * D_N) { o1[i] = f2bf(w1[i]); o2[i] = f2bf(w2[i]); }
}

// ---------------------------------------------------------------------------
// Shared mini-GEMM: block tile 128(rows) x 64(cols), NT form (both operands
// k-contiguous bf16). 4 waves as row strips of 32; per-wave 2x4 grid of
// 16x16 MFMA tiles. LDS stride 72 ushorts = 144 B (16B-aligned rows, only
// 2-way bank aliasing which is free). acc NOT zeroed here.
// ---------------------------------------------------------------------------
__device__ __forceinline__ void mm_tile(
    const unsigned short* Ag, const unsigned short* Bg,
    int aRow0, int bRow0, int K,
    unsigned short* Al, unsigned short* Bl, v4f acc[2][4])
{
    int tid = threadIdx.x;
    int lane = tid & 63, wave = tid >> 6, quad = lane >> 4, col = lane & 15;
    for (int kc = 0; kc < K; kc += 64) {
        __syncthreads();   // protect LDS from previous reads
        #pragma unroll
        for (int s = 0; s < 4; s++) {        // A: 128 rows x 64 k = 1024 x 16B
            int slot = s * 256 + tid;
            int row = slot >> 3, kg = slot & 7;
            uint4 v = *(const uint4*)(Ag + (size_t)(aRow0 + row) * K + kc + kg * 8);
            *(uint4*)(Al + row * 72 + kg * 8) = v;
        }
        #pragma unroll
        for (int s = 0; s < 2; s++) {        // B: 64 rows x 64 k
            int slot = s * 256 + tid;
            int row = slot >> 3, kg = slot & 7;
            uint4 v = *(const uint4*)(Bg + (size_t)(bRow0 + row) * K + kc + kg * 8);
            *(uint4*)(Bl + row * 72 + kg * 8) = v;
        }
        __syncthreads();
        #pragma unroll
        for (int kk = 0; kk < 2; kk++) {     // two K=32 MFMA steps per chunk
            v8s af[2], bf[4];
            #pragma unroll
            for (int tr = 0; tr < 2; tr++)
                af[tr] = *(const v8s*)(Al + (wave * 32 + tr * 16 + col) * 72 + kk * 32 + quad * 8);
            #pragma unroll
            for (int tc = 0; tc < 4; tc++)
                bf[tc] = *(const v8s*)(Bl + (tc * 16 + col) * 72 + kk * 32 + quad * 8);
            #pragma unroll
            for (int tr = 0; tr < 2; tr++)
                #pragma unroll
                for (int tc = 0; tc < 4; tc++)
                    acc[tr][tc] = __builtin_amdgcn_mfma_f32_16x16x32_bf16(
                        af[tr], bf[tc], acc[tr][tc], 0, 0, 0);
        }
    }
}

// ---------------------------------------------------------------------------
// Kernel 3: fz = z @ W^T + b  -> bf16 [4096][256].  grid (32, 4)
// ---------------------------------------------------------------------------
__global__ __launch_bounds__(256) void fz_gemm(
    const unsigned short* __restrict__ zb, const unsigned short* __restrict__ wb,
    const float* __restrict__ bias, unsigned short* __restrict__ outz)
{
    __shared__ unsigned short Al[128 * 72];
    __shared__ unsigned short Bl[64 * 72];
    v4f acc[2][4];
    #pragma unroll
    for (int i = 0; i < 2; i++)
        #pragma unroll
        for (int j = 0; j < 4; j++) acc[i][j] = (v4f){0.f, 0.f, 0.f, 0.f};
    int mBase = blockIdx.x * 128, nBase = blockIdx.y * 64;
    mm_tile(zb, wb, mBase, nBase, D_N, Al, Bl, acc);
    int tid = threadIdx.x, lane = tid & 63, wave = tid >> 6, quad = lane >> 4, col = lane & 15;
    #pragma unroll
    for (int tr = 0; tr < 2; tr++)
        #pragma unroll
        for (int tc = 0; tc < 4; tc++) {
            int gcol = nBase + tc * 16 + col;
            float bv = bias[gcol];
            #pragma unroll
            for (int reg = 0; reg < 4; reg++) {
                int grow = mBase + wave * 32 + tr * 16 + quad * 4 + reg;
                outz[(size_t)grow * HID_N + gcol] = f2bf(acc[tr][tc][reg] + bv);
            }
        }
}

// ---------------------------------------------------------------------------
// Kernel 4: per-row softmax over gathered logits; accumulate class sums.
// grid 64 blocks x 64 rows each.
// ---------------------------------------------------------------------------
__global__ __launch_bounds__(256) void softmax_mean(
    const float* __restrict__ logits, const int* __restrict__ oldi,
    const int* __restrict__ newi, float* __restrict__ msums)
{
    __shared__ float red[256];
    __shared__ float accs[NCLS];
    __shared__ int act[NCLS];
    int tid = threadIdx.x;
    if (tid < NCLS) { accs[tid] = 0.0f; act[tid] = (tid < 100) ? oldi[tid] : newi[tid - 100]; }
    __syncthreads();
    int r0 = blockIdx.x * 64;
    for (int i = 0; i < 64; i++) {
        const float* lr = logits + (size_t)(r0 + i) * NCLS;
        float x = (tid < NCLS) ? lr[act[tid]] : -3.0e38f;
        red[tid] = x; __syncthreads();
        for (int s = 128; s > 0; s >>= 1) { if (tid < s) red[tid] = fmaxf(red[tid], red[tid + s]); __syncthreads(); }
        float m = red[0]; __syncthreads();
        float e = (tid < NCLS) ? __expf(x - m) : 0.0f;
        red[tid] = e; __syncthreads();
        for (int s = 128; s > 0; s >>= 1) { if (tid < s) red[tid] += red[tid + s]; __syncthreads(); }
        float sm = red[0]; __syncthreads();
        if (tid < NCLS) accs[tid] += e / sm;
    }
    __syncthreads();
    if (tid < NCLS) atomicAdd(&msums[tid], accs[tid]);
}

// ---------------------------------------------------------------------------
// Kernel 5: fused contrastive main. grid (32 i-blocks, 32 j-chunks).
// Each block: 128 rows x 256-col... (2 j-tiles of 64). Row-strip waves =>
// each row's state lives in exactly one wave; 16-lane butterfly at the end.
// Emits per-(row, chunk) partials: l = sum exp(attn) over mask,
// a = sum exp(attn)*sim, d = sum_{j!=i} exp(sim/tau), nn = mask count.
// ---------------------------------------------------------------------------
__global__ __launch_bounds__(256) void main_fused(
    const unsigned short* __restrict__ zn, const unsigned short* __restrict__ bn,
    const unsigned short* __restrict__ f1z, const unsigned short* __restrict__ f2z,
    float* __restrict__ partials)
{
    __shared__ unsigned short Al[128 * 72];
    __shared__ unsigned short Bl[64 * 72];
    int tid = threadIdx.x, lane = tid & 63, wave = tid >> 6, quad = lane >> 4, col = lane & 15;
    int ib = blockIdx.x, jc = blockIdx.y;
    int rBase = ib * 128 + wave * 32;

    float lsum[8], asum[8], dsum[8]; int nn[8];
    #pragma unroll
    for (int i = 0; i < 8; i++) { lsum[i] = 0.f; asum[i] = 0.f; dsum[i] = 0.f; nn[i] = 0; }

    for (int jt = 0; jt < 2; jt++) {
        int cBase = jc * 128 + jt * 64;

        // --- base_sim tile -> mask bits ---
        v4f bacc[2][4];
        #pragma unroll
        for (int i = 0; i < 2; i++)
            #pragma unroll
            for (int j = 0; j < 4; j++) bacc[i][j] = (v4f){0.f, 0.f, 0.f, 0.f};
        mm_tile(bn, bn, ib * 128, cBase, D_N, Al, Bl, bacc);
        unsigned int mb = 0;
        #pragma unroll
        for (int tr = 0; tr < 2; tr++)
            #pragma unroll
            for (int tc = 0; tc < 4; tc++)
                #pragma unroll
                for (int reg = 0; reg < 4; reg++) {
                    int grow = rBase + tr * 16 + quad * 4 + reg;
                    int gcol = cBase + tc * 16 + col;
                    if (bacc[tr][tc][reg] > 0.05f && grow != gcol)
                        mb |= 1u << (tr * 16 + tc * 4 + reg);
                }

        // --- sim tile ---
        v4f sacc[2][4];
        #pragma unroll
        for (int i = 0; i < 2; i++)
            #pragma unroll
            for (int j = 0; j < 4; j++) sacc[i][j] = (v4f){0.f, 0.f, 0.f, 0.f};
        mm_tile(zn, zn, ib * 128, cBase, D_N, Al, Bl, sacc);

        // --- attn tile ---
        v4f aacc[2][4];
        #pragma unroll
        for (int i = 0; i < 2; i++)
            #pragma unroll
            for (int j = 0; j < 4; j++) aacc[i][j] = (v4f){0.f, 0.f, 0.f, 0.f};
        mm_tile(f1z, f2z, ib * 128, cBase, HID_N, Al, Bl, aacc);

        // --- combine ---
        #pragma unroll
        for (int tr = 0; tr < 2; tr++)
            #pragma unroll
            for (int tc = 0; tc < 4; tc++)
                #pragma unroll
                for (int reg = 0; reg < 4; reg++) {
                    int sidx = tr * 4 + reg;
                    float sv = sacc[tr][tc][reg];
                    int grow = rBase + tr * 16 + quad * 4 + reg;
                    int gcol = cBase + tc * 16 + col;
                    float es = __expf(sv * 10.0f);            // exp(sim/TAU)
                    if (grow != gcol) dsum[sidx] += es;
                    if (mb & (1u << (tr * 16 + tc * 4 + reg))) {
                        float e = __expf(aacc[tr][tc][reg]);  // no max-shift needed
                        lsum[sidx] += e;
                        asum[sidx] += e * sv;
                        nn[sidx] += 1;
                    }
                }
    }

    // merge the 16 column-lanes per row; lane col==0 stores partials
    #pragma unroll
    for (int i = 0; i < 8; i++) {
        float nf = (float)nn[i];
        #pragma unroll
        for (int m = 1; m < 16; m <<= 1) {
            lsum[i] += __shfl_xor(lsum[i], m);
            asum[i] += __shfl_xor(asum[i], m);
            dsum[i] += __shfl_xor(dsum[i], m);
            nf      += __shfl_xor(nf, m);
        }
        if (col == 0) {
            int row = rBase + (i >> 2) * 16 + quad * 4 + (i & 3);
            float4 v; v.x = lsum[i]; v.y = asum[i]; v.z = dsum[i]; v.w = nf;
            *(float4*)(partials + ((size_t)row * 32 + jc) * 4) = v;
        }
    }
}

// ---------------------------------------------------------------------------
// Kernel 6: reduce per-row partials over 32 chunks -> per_sample; atomic sums
// ---------------------------------------------------------------------------
__global__ __launch_bounds__(256) void row_reduce(
    const float* __restrict__ partials, float* __restrict__ acc)
{
    int tid = threadIdx.x;
    int r = blockIdx.x * 256 + tid;
    const float4* p = (const float4*)partials + (size_t)r * 32;
    float L = 0.f, A = 0.f, Dn = 0.f, NN = 0.f;
    #pragma unroll
    for (int c = 0; c < 32; c++) { float4 v = p[c]; L += v.x; A += v.y; Dn += v.z; NN += v.w; }
    float per = 0.f, val = 0.f;
    if (NN > 0.5f) {
        per = (logf(Dn + 1e-8f) - 10.0f * (A / L)) / NN;  // loss_i / nn
        val = 1.0f;
    }
    __shared__ float r1[256], r2[256];
    r1[tid] = per; r2[tid] = val; __syncthreads();
    for (int s = 128; s > 0; s >>= 1) {
        if (tid < s) { r1[tid] += r1[tid + s]; r2[tid] += r2[tid + s]; }
        __syncthreads();
    }
    if (tid == 0) { atomicAdd(&acc[0], r1[0]); atomicAdd(&acc[1], r2[0]); }
}

// ---------------------------------------------------------------------------
// Kernel 7: entropy loss + final combine -> d_out[0]
// ---------------------------------------------------------------------------
__global__ __launch_bounds__(256) void finalize_k(
    const float* __restrict__ msums, const float* __restrict__ acc,
    float* __restrict__ out)
{
    __shared__ float red[256];
    __shared__ float bcast[2];
    int tid = threadIdx.x;
    float p = (tid < NCLS) ? msums[tid] * (1.0f / 4096.0f) : 0.0f;

    red[tid] = (tid < 100) ? p : 0.0f; __syncthreads();
    for (int s = 128; s > 0; s >>= 1) { if (tid < s) red[tid] += red[tid + s]; __syncthreads(); }
    if (tid == 0) bcast[0] = red[0];
    __syncthreads();
    red[tid] = (tid >= 100 && tid < NCLS) ? p : 0.0f; __syncthreads();
    for (int s = 128; s > 0; s >>= 1) { if (tid < s) red[tid] += red[tid + s]; __syncthreads(); }
    if (tid == 0) bcast[1] = red[0];
    __syncthreads();
    float p_old = bcast[0], p_new = bcast[1];

    float t = 0.0f;
    if (tid < 100)       { float q = p / (p_old + 1e-8f); t = q * logf(q + 1e-8f); }
    else if (tid < NCLS) { float q = p / (p_new + 1e-8f); t = q * logf(q + 1e-8f); }
    red[tid] = t; __syncthreads();
    for (int s = 128; s > 0; s >>= 1) { if (tid < s) red[tid] += red[tid + s]; __syncthreads(); }

    if (tid == 0) {
        float loss_inter = p_old * logf(p_old + 1e-8f) + p_new * logf(p_new + 1e-8f)
                           + 0.69314718056f;                     // + log 2
        float loss_entropy = loss_inter + red[0] + 2.0f * 4.60517018599f;  // + 2*log(100)
        float cnt = acc[1];
        float lc = (cnt > 0.5f) ? acc[0] / cnt : 0.0f;
        out[0] = loss_entropy + lc;
    }
}

// ---------------------------------------------------------------------------
extern "C" void kernel_launch(void* const* d_in, const int* in_sizes, int n_in,
                              void* d_out, int out_size, void* d_ws, size_t ws_size,
                              hipStream_t stream)
{
    const float* z_u    = (const float*)d_in[0];
    const float* logits = (const float*)d_in[1];
    const int*   oldi   = (const int*)d_in[2];
    const int*   newi   = (const int*)d_in[3];
    const float* basef  = (const float*)d_in[4];
    const float* f1w    = (const float*)d_in[5];
    const float* f1b    = (const float*)d_in[6];
    const float* f2w    = (const float*)d_in[7];
    const float* f2b    = (const float*)d_in[8];
    float* out = (float*)d_out;

    unsigned short* zn   = (unsigned short*)d_ws;          // [B][D] bf16
    unsigned short* bn   = zn  + (size_t)B_N * D_N;        // [B][D]
    unsigned short* zb   = bn  + (size_t)B_N * D_N;        // [B][D]
    unsigned short* w1b  = zb  + (size_t)B_N * D_N;        // [HID][D]
    unsigned short* w2b  = w1b + (size_t)HID_N * D_N;
    unsigned short* f1z  = w2b + (size_t)HID_N * D_N;      // [B][HID]
    unsigned short* f2z  = f1z + (size_t)B_N * HID_N;
    float* partials = (float*)(f2z + (size_t)B_N * HID_N); // [B][32][4]
    float* msums    = partials + (size_t)B_N * 32 * 4;     // [200]
    float* accums   = msums + NCLS;                        // [2]

    hipMemsetAsync(msums, 0, (NCLS + 8) * sizeof(float), stream);

    normalize_k<<<B_N, 256, 0, stream>>>(z_u, basef, zn, bn, zb);
    convert_w<<<(HID_N * D_N + 255) / 256, 256, 0, stream>>>(f1w, f2w, w1b, w2b);
    fz_gemm<<<dim3(B_N / 128, HID_N / 64), 256, 0, stream>>>(zb, w1b, f1b, f1z);
    fz_gemm<<<dim3(B_N / 128, HID_N / 64), 256, 0, stream>>>(zb, w2b, f2b, f2z);
    softmax_mean<<<64, 256, 0, stream>>>(logits, oldi, newi, msums);
    main_fused<<<dim3(32, 32), 256, 0, stream>>>(zn, bn, f1z, f2z, partials);
    row_reduce<<<B_N / 256, 256, 0, stream>>>(partials, accums);
    finalize_k<<<1, 256, 0, stream>>>(msums, accums, out);
}

// Round 2
// 220.130 us; speedup vs baseline: 2.1100x; 2.1100x over previous
//
#include <hip/hip_runtime.h>

// ---------------------------------------------------------------------------
// Debiased Representation Loss — fused MI355X implementation (R2).
// Heavy part: three pairwise 4096x4096 matrices (base_sim mask K=768,
// sim K=768, attn K=256) fused flash-style. R2: global_load_lds width-16
// staging with XOR-swizzled unpadded LDS (stride 64), grid (32,64) for
// 8 blocks/CU of work, wave-parallel softmax_mean.
// ---------------------------------------------------------------------------

#define B_N   4096
#define D_N   768
#define HID_N 256
#define NCLS  200

typedef __attribute__((ext_vector_type(8))) short v8s;   // 8 x bf16 (4 VGPRs)
typedef __attribute__((ext_vector_type(4))) float v4f;   // MFMA accumulator

// round-to-nearest-even fp32 -> bf16
__device__ __forceinline__ unsigned short f2bf(float x) {
    unsigned int u = __float_as_uint(x);
    unsigned int r = (u + 0x7FFFu + ((u >> 16) & 1u)) >> 16;
    return (unsigned short)r;
}

// async global->LDS, 16 B per lane; lane i lands at ldsbase + i*16
__device__ __forceinline__ void gld16(const unsigned short* g, unsigned short* l) {
    __builtin_amdgcn_global_load_lds(
        (__attribute__((address_space(1))) void*)g,
        (__attribute__((address_space(3))) void*)l, 16, 0, 0);
}

// ---------------------------------------------------------------------------
// Kernel 1: L2-normalize z_u and base_features rows; emit bf16 copies.
// ---------------------------------------------------------------------------
__global__ __launch_bounds__(256) void normalize_k(
    const float* __restrict__ z, const float* __restrict__ base,
    unsigned short* __restrict__ zn, unsigned short* __restrict__ bn,
    unsigned short* __restrict__ zb)
{
    int row = blockIdx.x, tid = threadIdx.x;
    __shared__ float ws1[4], ws2[4];
    const float* zr = z    + (size_t)row * D_N;
    const float* br = base + (size_t)row * D_N;
    float z0 = zr[tid], z1 = zr[tid + 256], z2 = zr[tid + 512];
    float b0 = br[tid], b1 = br[tid + 256], b2 = br[tid + 512];
    float s1 = z0*z0 + z1*z1 + z2*z2;
    float s2 = b0*b0 + b1*b1 + b2*b2;
    #pragma unroll
    for (int m = 32; m > 0; m >>= 1) { s1 += __shfl_xor(s1, m); s2 += __shfl_xor(s2, m); }
    if ((tid & 63) == 0) { ws1[tid >> 6] = s1; ws2[tid >> 6] = s2; }
    __syncthreads();
    float t1 = ws1[0] + ws1[1] + ws1[2] + ws1[3];
    float t2 = ws2[0] + ws2[1] + ws2[2] + ws2[3];
    float sc1 = 1.0f / fmaxf(sqrtf(t1), 1e-12f);
    float sc2 = 1.0f / fmaxf(sqrtf(t2), 1e-12f);
    size_t o = (size_t)row * D_N;
    zn[o+tid] = f2bf(z0*sc1); zn[o+tid+256] = f2bf(z1*sc1); zn[o+tid+512] = f2bf(z2*sc1);
    bn[o+tid] = f2bf(b0*sc2); bn[o+tid+256] = f2bf(b1*sc2); bn[o+tid+512] = f2bf(b2*sc2);
    zb[o+tid] = f2bf(z0);     zb[o+tid+256] = f2bf(z1);     zb[o+tid+512] = f2bf(z2);
}

// ---------------------------------------------------------------------------
// Kernel 2: convert f1_w / f2_w to bf16
// ---------------------------------------------------------------------------
__global__ __launch_bounds__(256) void convert_w(
    const float* __restrict__ w1, const float* __restrict__ w2,
    unsigned short* __restrict__ o1, unsigned short* __restrict__ o2)
{
    int i = blockIdx.x * 256 + threadIdx.x;
    if (i < HID_N * D_N) { o1[i] = f2bf(w1[i]); o2[i] = f2bf(w2[i]); }
}

// ---------------------------------------------------------------------------
// Shared mini-GEMM v2: block tile 128(rows) x 64(cols), NT bf16.
// global_load_lds width-16 staging; LDS stride 64 ushorts (unpadded, as
// required by the wave-uniform-base+lane*16 semantics) with XOR swizzle:
// physical kblock = logical kblock ^ (row & 7)  -> fragment ds_read_b128
// stays at the 8-access/bank minimum. Two barriers per BK=64 chunk.
// ---------------------------------------------------------------------------
__device__ __forceinline__ void mm_tile2(
    const unsigned short* __restrict__ Ag, const unsigned short* __restrict__ Bg,
    int aRow0, int bRow0, int K,
    unsigned short* Al, unsigned short* Bl, v4f acc[2][4])
{
    const int tid = threadIdx.x;
    const int lane = tid & 63, wave = tid >> 6, quad = lane >> 4, col = lane & 15;
    const int r8 = lane >> 3;                 // 0..7: row within 8-row group
    const int kbl = (lane & 7) ^ r8;          // logical k-block this lane fetches
    const int sw  = col & 7;                  // read-side swizzle key
    for (int kc = 0; kc < K; kc += 64) {
        __syncthreads();                      // LDS reads of prev chunk done
        #pragma unroll
        for (int s = 0; s < 4; s++) {         // A: 128 rows x 64 k
            int rowbase = s * 32 + wave * 8;
            gld16(Ag + (size_t)(aRow0 + rowbase + r8) * K + kc + kbl * 8,
                  Al + rowbase * 64);
        }
        #pragma unroll
        for (int s = 0; s < 2; s++) {         // B: 64 rows x 64 k
            int rowbase = s * 32 + wave * 8;
            gld16(Bg + (size_t)(bRow0 + rowbase + r8) * K + kc + kbl * 8,
                  Bl + rowbase * 64);
        }
        __syncthreads();                      // staging drained (vmcnt)
        #pragma unroll
        for (int kk = 0; kk < 2; kk++) {      // two K=32 MFMA steps
            int ko = (((kk << 2) + quad) ^ sw) << 3;   // swizzled ushort offset
            v8s af[2], bf[4];
            #pragma unroll
            for (int tr = 0; tr < 2; tr++)
                af[tr] = *(const v8s*)(Al + (wave * 32 + tr * 16 + col) * 64 + ko);
            #pragma unroll
            for (int tc = 0; tc < 4; tc++)
                bf[tc] = *(const v8s*)(Bl + (tc * 16 + col) * 64 + ko);
            #pragma unroll
            for (int tr = 0; tr < 2; tr++)
                #pragma unroll
                for (int tc = 0; tc < 4; tc++)
                    acc[tr][tc] = __builtin_amdgcn_mfma_f32_16x16x32_bf16(
                        af[tr], bf[tc], acc[tr][tc], 0, 0, 0);
        }
    }
}

// ---------------------------------------------------------------------------
// Kernel 3: fz = z @ W^T + b  -> bf16 [4096][256].  grid (32, 4)
// ---------------------------------------------------------------------------
__global__ __launch_bounds__(256, 4) void fz_gemm(
    const unsigned short* __restrict__ zb, const unsigned short* __restrict__ wb,
    const float* __restrict__ bias, unsigned short* __restrict__ outz)
{
    __shared__ __align__(16) unsigned short Al[128 * 64];
    __shared__ __align__(16) unsigned short Bl[64 * 64];
    v4f acc[2][4];
    #pragma unroll
    for (int i = 0; i < 2; i++)
        #pragma unroll
        for (int j = 0; j < 4; j++) acc[i][j] = (v4f){0.f, 0.f, 0.f, 0.f};
    int mBase = blockIdx.x * 128, nBase = blockIdx.y * 64;
    mm_tile2(zb, wb, mBase, nBase, D_N, Al, Bl, acc);
    int tid = threadIdx.x, lane = tid & 63, wave = tid >> 6, quad = lane >> 4, col = lane & 15;
    #pragma unroll
    for (int tr = 0; tr < 2; tr++)
        #pragma unroll
        for (int tc = 0; tc < 4; tc++) {
            int gcol = nBase + tc * 16 + col;
            float bv = bias[gcol];
            #pragma unroll
            for (int reg = 0; reg < 4; reg++) {
                int grow = mBase + wave * 32 + tr * 16 + quad * 4 + reg;
                outz[(size_t)grow * HID_N + gcol] = f2bf(acc[tr][tc][reg] + bv);
            }
        }
}

// ---------------------------------------------------------------------------
// Kernel 4: per-row softmax over gathered logits. Wave-per-row, shuffle-only
// reductions (no inner barriers). grid 256 blocks x 16 rows.
// ---------------------------------------------------------------------------
__global__ __launch_bounds__(256) void softmax_mean(
    const float* __restrict__ logits, const int* __restrict__ oldi,
    const int* __restrict__ newi, float* __restrict__ msums)
{
    __shared__ int act[256];
    __shared__ float accs[4][256];
    int tid = threadIdx.x, lane = tid & 63, wave = tid >> 6;
    if (tid < NCLS) act[tid] = (tid < 100) ? oldi[tid] : newi[tid - 100];
    accs[0][tid] = 0.f; accs[1][tid] = 0.f; accs[2][tid] = 0.f; accs[3][tid] = 0.f;
    __syncthreads();
    int a0 = act[lane], a1 = act[lane + 64], a2 = act[lane + 128];
    int a3 = (lane < 8) ? act[lane + 192] : 0;
    int r0 = blockIdx.x * 16 + wave * 4;
    float c0 = 0.f, c1 = 0.f, c2 = 0.f, c3 = 0.f;
    for (int i = 0; i < 4; i++) {
        const float* lr = logits + (size_t)(r0 + i) * NCLS;
        float x0 = lr[a0], x1 = lr[a1], x2 = lr[a2];
        float x3 = (lane < 8) ? lr[a3] : -3.0e38f;
        float m = fmaxf(fmaxf(x0, x1), fmaxf(x2, x3));
        #pragma unroll
        for (int s = 32; s > 0; s >>= 1) m = fmaxf(m, __shfl_xor(m, s));
        float e0 = __expf(x0 - m), e1 = __expf(x1 - m), e2 = __expf(x2 - m);
        float e3 = (lane < 8) ? __expf(x3 - m) : 0.f;
        float sm = e0 + e1 + e2 + e3;
        #pragma unroll
        for (int s = 32; s > 0; s >>= 1) sm += __shfl_xor(sm, s);
        float inv = 1.0f / sm;
        c0 += e0 * inv; c1 += e1 * inv; c2 += e2 * inv; c3 += e3 * inv;
    }
    accs[wave][lane] = c0; accs[wave][lane + 64] = c1; accs[wave][lane + 128] = c2;
    if (lane < 8) accs[wave][lane + 192] = c3;
    __syncthreads();
    if (tid < NCLS)
        atomicAdd(&msums[tid], accs[0][tid] + accs[1][tid] + accs[2][tid] + accs[3][tid]);
}

// ---------------------------------------------------------------------------
// Kernel 5: fused contrastive main. grid (32 i-blocks, 64 j-blocks); each
// block = 128 rows x 64 cols. Row-strip waves (32 rows each) => each row's
// state lives in one wave; 16-lane butterfly merge; per-(row, jc) partials:
// l = sum exp(attn) over mask, a = sum exp(attn)*sim, d = sum exp(sim/tau),
// nn = mask count. attn logits are small (|.|<~35) so no online max needed.
// ---------------------------------------------------------------------------
__global__ __launch_bounds__(256, 4) void main_fused(
    const unsigned short* __restrict__ zn, const unsigned short* __restrict__ bn,
    const unsigned short* __restrict__ f1z, const unsigned short* __restrict__ f2z,
    float* __restrict__ partials)
{
    __shared__ __align__(16) unsigned short Al[128 * 64];
    __shared__ __align__(16) unsigned short Bl[64 * 64];
    int tid = threadIdx.x, lane = tid & 63, wave = tid >> 6, quad = lane >> 4, col = lane & 15;
    int ib = blockIdx.x, jc = blockIdx.y;
    int rBase = ib * 128 + wave * 32, cBase = jc * 64;

    // --- base_sim tile -> mask bits ---
    v4f bacc[2][4];
    #pragma unroll
    for (int i = 0; i < 2; i++)
        #pragma unroll
        for (int j = 0; j < 4; j++) bacc[i][j] = (v4f){0.f, 0.f, 0.f, 0.f};
    mm_tile2(bn, bn, ib * 128, cBase, D_N, Al, Bl, bacc);
    unsigned int mb = 0;
    #pragma unroll
    for (int tr = 0; tr < 2; tr++)
        #pragma unroll
        for (int tc = 0; tc < 4; tc++)
            #pragma unroll
            for (int reg = 0; reg < 4; reg++) {
                int grow = rBase + tr * 16 + quad * 4 + reg;
                int gcol = cBase + tc * 16 + col;
                if (bacc[tr][tc][reg] > 0.05f && grow != gcol)
                    mb |= 1u << (tr * 16 + tc * 4 + reg);
            }

    // --- sim tile ---
    v4f sacc[2][4];
    #pragma unroll
    for (int i = 0; i < 2; i++)
        #pragma unroll
        for (int j = 0; j < 4; j++) sacc[i][j] = (v4f){0.f, 0.f, 0.f, 0.f};
    mm_tile2(zn, zn, ib * 128, cBase, D_N, Al, Bl, sacc);

    // --- attn tile ---
    v4f aacc[2][4];
    #pragma unroll
    for (int i = 0; i < 2; i++)
        #pragma unroll
        for (int j = 0; j < 4; j++) aacc[i][j] = (v4f){0.f, 0.f, 0.f, 0.f};
    mm_tile2(f1z, f2z, ib * 128, cBase, HID_N, Al, Bl, aacc);

    // --- combine ---
    float lsum[8], asum[8], dsum[8], nnf[8];
    #pragma unroll
    for (int i = 0; i < 8; i++) { lsum[i] = 0.f; asum[i] = 0.f; dsum[i] = 0.f; nnf[i] = 0.f; }
    #pragma unroll
    for (int tr = 0; tr < 2; tr++)
        #pragma unroll
        for (int tc = 0; tc < 4; tc++)
            #pragma unroll
            for (int reg = 0; reg < 4; reg++) {
                int sidx = tr * 4 + reg;
                float sv = sacc[tr][tc][reg];
                int grow = rBase + tr * 16 + quad * 4 + reg;
                int gcol = cBase + tc * 16 + col;
                float es = __expf(sv * 10.0f);            // exp(sim/TAU)
                if (grow != gcol) dsum[sidx] += es;
                if (mb & (1u << (tr * 16 + tc * 4 + reg))) {
                    float e = __expf(aacc[tr][tc][reg]);
                    lsum[sidx] += e;
                    asum[sidx] += e * sv;
                    nnf[sidx] += 1.f;
                }
            }

    #pragma unroll
    for (int i = 0; i < 8; i++) {
        #pragma unroll
        for (int m = 1; m < 16; m <<= 1) {
            lsum[i] += __shfl_xor(lsum[i], m);
            asum[i] += __shfl_xor(asum[i], m);
            dsum[i] += __shfl_xor(dsum[i], m);
            nnf[i]  += __shfl_xor(nnf[i], m);
        }
        if (col == 0) {
            int row = rBase + (i >> 2) * 16 + quad * 4 + (i & 3);
            float4 v; v.x = lsum[i]; v.y = asum[i]; v.z = dsum[i]; v.w = nnf[i];
            *(float4*)(partials + ((size_t)row * 64 + jc) * 4) = v;
        }
    }
}

// ---------------------------------------------------------------------------
// Kernel 6: reduce per-row partials over 64 chunks -> per_sample; atomic sums
// ---------------------------------------------------------------------------
__global__ __launch_bounds__(256) void row_reduce(
    const float* __restrict__ partials, float* __restrict__ acc)
{
    int tid = threadIdx.x;
    int r = blockIdx.x * 256 + tid;
    const float4* p = (const float4*)partials + (size_t)r * 64;
    float L = 0.f, A = 0.f, Dn = 0.f, NN = 0.f;
    #pragma unroll
    for (int c = 0; c < 64; c++) { float4 v = p[c]; L += v.x; A += v.y; Dn += v.z; NN += v.w; }
    float per = 0.f, val = 0.f;
    if (NN > 0.5f) {
        per = (logf(Dn + 1e-8f) - 10.0f * (A / L)) / NN;
        val = 1.0f;
    }
    __shared__ float r1[256], r2[256];
    r1[tid] = per; r2[tid] = val; __syncthreads();
    for (int s = 128; s > 0; s >>= 1) {
        if (tid < s) { r1[tid] += r1[tid + s]; r2[tid] += r2[tid + s]; }
        __syncthreads();
    }
    if (tid == 0) { atomicAdd(&acc[0], r1[0]); atomicAdd(&acc[1], r2[0]); }
}

// ---------------------------------------------------------------------------
// Kernel 7: entropy loss + final combine -> d_out[0]
// ---------------------------------------------------------------------------
__global__ __launch_bounds__(256) void finalize_k(
    const float* __restrict__ msums, const float* __restrict__ acc,
    float* __restrict__ out)
{
    __shared__ float red[256];
    __shared__ float bcast[2];
    int tid = threadIdx.x;
    float p = (tid < NCLS) ? msums[tid] * (1.0f / 4096.0f) : 0.0f;

    red[tid] = (tid < 100) ? p : 0.0f; __syncthreads();
    for (int s = 128; s > 0; s >>= 1) { if (tid < s) red[tid] += red[tid + s]; __syncthreads(); }
    if (tid == 0) bcast[0] = red[0];
    __syncthreads();
    red[tid] = (tid >= 100 && tid < NCLS) ? p : 0.0f; __syncthreads();
    for (int s = 128; s > 0; s >>= 1) { if (tid < s) red[tid] += red[tid + s]; __syncthreads(); }
    if (tid == 0) bcast[1] = red[0];
    __syncthreads();
    float p_old = bcast[0], p_new = bcast[1];

    float t = 0.0f;
    if (tid < 100)       { float q = p / (p_old + 1e-8f); t = q * logf(q + 1e-8f); }
    else if (tid < NCLS) { float q = p / (p_new + 1e-8f); t = q * logf(q + 1e-8f); }
    red[tid] = t; __syncthreads();
    for (int s = 128; s > 0; s >>= 1) { if (tid < s) red[tid] += red[tid + s]; __syncthreads(); }

    if (tid == 0) {
        float loss_inter = p_old * logf(p_old + 1e-8f) + p_new * logf(p_new + 1e-8f)
                           + 0.69314718056f;
        float loss_entropy = loss_inter + red[0] + 2.0f * 4.60517018599f;
        float cnt = acc[1];
        float lc = (cnt > 0.5f) ? acc[0] / cnt : 0.0f;
        out[0] = loss_entropy + lc;
    }
}

// ---------------------------------------------------------------------------
extern "C" void kernel_launch(void* const* d_in, const int* in_sizes, int n_in,
                              void* d_out, int out_size, void* d_ws, size_t ws_size,
                              hipStream_t stream)
{
    const float* z_u    = (const float*)d_in[0];
    const float* logits = (const float*)d_in[1];
    const int*   oldi   = (const int*)d_in[2];
    const int*   newi   = (const int*)d_in[3];
    const float* basef  = (const float*)d_in[4];
    const float* f1w    = (const float*)d_in[5];
    const float* f1b    = (const float*)d_in[6];
    const float* f2w    = (const float*)d_in[7];
    const float* f2b    = (const float*)d_in[8];
    float* out = (float*)d_out;

    unsigned short* zn   = (unsigned short*)d_ws;          // [B][D] bf16
    unsigned short* bn   = zn  + (size_t)B_N * D_N;
    unsigned short* zb   = bn  + (size_t)B_N * D_N;
    unsigned short* w1b  = zb  + (size_t)B_N * D_N;        // [HID][D]
    unsigned short* w2b  = w1b + (size_t)HID_N * D_N;
    unsigned short* f1z  = w2b + (size_t)HID_N * D_N;      // [B][HID]
    unsigned short* f2z  = f1z + (size_t)B_N * HID_N;
    float* partials = (float*)(f2z + (size_t)B_N * HID_N); // [B][64][4]
    float* msums    = partials + (size_t)B_N * 64 * 4;     // [200]
    float* accums   = msums + NCLS;                        // [2]

    hipMemsetAsync(msums, 0, (NCLS + 8) * sizeof(float), stream);

    normalize_k<<<B_N, 256, 0, stream>>>(z_u, basef, zn, bn, zb);
    convert_w<<<(HID_N * D_N + 255) / 256, 256, 0, stream>>>(f1w, f2w, w1b, w2b);
    fz_gemm<<<dim3(B_N / 128, HID_N / 64), 256, 0, stream>>>(zb, w1b, f1b, f1z);
    fz_gemm<<<dim3(B_N / 128, HID_N / 64), 256, 0, stream>>>(zb, w2b, f2b, f2z);
    softmax_mean<<<256, 256, 0, stream>>>(logits, oldi, newi, msums);
    main_fused<<<dim3(32, 64), 256, 0, stream>>>(zn, bn, f1z, f2z, partials);
    row_reduce<<<B_N / 256, 256, 0, stream>>>(partials, accums);
    finalize_k<<<1, 256, 0, stream>>>(msums, accums, out);
}

// Round 3
// 214.908 us; speedup vs baseline: 2.1612x; 1.0243x over previous
//
#include <hip/hip_runtime.h>

// ---------------------------------------------------------------------------
// Debiased Representation Loss — fused MI355X implementation (R3).
// Heavy part: three pairwise 4096x4096 matrices (mask K=768, sim K=768,
// attn K=256) fused flash-style. R3: 128x128 block tile, 2x2 wave grid
// (64x64 per wave, 4x4 MFMA tiles) to cut LDS bytes/FLOP 1.5x; kernel-count
// reduction (convert_w folded into normalize, one fz launch, fused
// row_reduce+finalize via last-block atomic).
// ---------------------------------------------------------------------------

#define B_N   4096
#define D_N   768
#define HID_N 256
#define NCLS  200

typedef __attribute__((ext_vector_type(8))) short v8s;   // 8 x bf16 (4 VGPRs)
typedef __attribute__((ext_vector_type(4))) float v4f;   // MFMA accumulator

// round-to-nearest-even fp32 -> bf16
__device__ __forceinline__ unsigned short f2bf(float x) {
    unsigned int u = __float_as_uint(x);
    unsigned int r = (u + 0x7FFFu + ((u >> 16) & 1u)) >> 16;
    return (unsigned short)r;
}
__device__ __forceinline__ float bf2f(unsigned short h) {
    return __uint_as_float((unsigned int)h << 16);
}

// async global->LDS, 16 B per lane; lane i lands at ldsbase + i*16
__device__ __forceinline__ void gld16(const unsigned short* g, unsigned short* l) {
    __builtin_amdgcn_global_load_lds(
        (__attribute__((address_space(1))) void*)g,
        (__attribute__((address_space(3))) void*)l, 16, 0, 0);
}

// ---------------------------------------------------------------------------
// Kernel 1: L2-normalize z_u and base_features rows; emit bf16 copies.
// Blocks >= 4096 convert f1_w / f2_w to bf16 instead.
// ---------------------------------------------------------------------------
__global__ __launch_bounds__(256) void normalize_k(
    const float* __restrict__ z, const float* __restrict__ base,
    const float* __restrict__ w1, const float* __restrict__ w2,
    unsigned short* __restrict__ zn, unsigned short* __restrict__ bn,
    unsigned short* __restrict__ zb,
    unsigned short* __restrict__ o1, unsigned short* __restrict__ o2)
{
    int tid = threadIdx.x;
    if (blockIdx.x >= B_N) {                     // weight conversion tail
        int b2 = blockIdx.x - B_N;               // 0..7
        const float* src = (b2 < 4) ? w1 : w2;
        unsigned short* dst = (b2 < 4) ? o1 : o2;
        int base2 = (b2 & 3) * 49152 + tid;      // 196608/4 per block
        #pragma unroll 4
        for (int i = 0; i < 192; i++) dst[base2 + i * 256] = f2bf(src[base2 + i * 256]);
        return;
    }
    int row = blockIdx.x;
    __shared__ float ws1[4], ws2[4];
    const float* zr = z    + (size_t)row * D_N;
    const float* br = base + (size_t)row * D_N;
    float z0 = zr[tid], z1 = zr[tid + 256], z2 = zr[tid + 512];
    float b0 = br[tid], b1 = br[tid + 256], b2 = br[tid + 512];
    float s1 = z0*z0 + z1*z1 + z2*z2;
    float s2 = b0*b0 + b1*b1 + b2*b2;
    #pragma unroll
    for (int m = 32; m > 0; m >>= 1) { s1 += __shfl_xor(s1, m); s2 += __shfl_xor(s2, m); }
    if ((tid & 63) == 0) { ws1[tid >> 6] = s1; ws2[tid >> 6] = s2; }
    __syncthreads();
    float t1 = ws1[0] + ws1[1] + ws1[2] + ws1[3];
    float t2 = ws2[0] + ws2[1] + ws2[2] + ws2[3];
    float sc1 = 1.0f / fmaxf(sqrtf(t1), 1e-12f);
    float sc2 = 1.0f / fmaxf(sqrtf(t2), 1e-12f);
    size_t o = (size_t)row * D_N;
    zn[o+tid] = f2bf(z0*sc1); zn[o+tid+256] = f2bf(z1*sc1); zn[o+tid+512] = f2bf(z2*sc1);
    bn[o+tid] = f2bf(b0*sc2); bn[o+tid+256] = f2bf(b1*sc2); bn[o+tid+512] = f2bf(b2*sc2);
    zb[o+tid] = f2bf(z0);     zb[o+tid+256] = f2bf(z1);     zb[o+tid+512] = f2bf(z2);
}

// ---------------------------------------------------------------------------
// Shared mini-GEMM v3: block tile 128(rows) x 128(cols), NT bf16.
// 2x2 wave grid, each wave 64x64 via 4x4 MFMA tiles. global_load_lds
// width-16 staging, XOR-swizzled unpadded LDS rows (stride 64 ushorts):
// physical kblock = logical kblock ^ (row & 7). Verified 0 bank conflicts
// with this scheme in R2.
// ---------------------------------------------------------------------------
__device__ __forceinline__ void mm_tile128(
    const unsigned short* __restrict__ Ag, const unsigned short* __restrict__ Bg,
    int aRow0, int bRow0, int K,
    unsigned short* Al, unsigned short* Bl, v4f acc[4][4])
{
    const int tid = threadIdx.x;
    const int lane = tid & 63, wave = tid >> 6, quad = lane >> 4, col = lane & 15;
    const int wr = wave >> 1, wc = wave & 1;
    const int r8 = lane >> 3;                 // row within 8-row staging group
    const int kbl = (lane & 7) ^ r8;          // logical k-block this lane fetches
    const int sw  = col & 7;                  // read-side swizzle key
    for (int kc = 0; kc < K; kc += 64) {
        __syncthreads();                      // LDS reads of prev chunk done
        #pragma unroll
        for (int s = 0; s < 4; s++) {         // A + B: 128 rows x 64 k each
            int rowbase = s * 32 + wave * 8;
            gld16(Ag + (size_t)(aRow0 + rowbase + r8) * K + kc + kbl * 8,
                  Al + rowbase * 64);
            gld16(Bg + (size_t)(bRow0 + rowbase + r8) * K + kc + kbl * 8,
                  Bl + rowbase * 64);
        }
        __syncthreads();                      // staging drained
        #pragma unroll
        for (int kk = 0; kk < 2; kk++) {      // two K=32 MFMA steps
            int ko = (((kk << 2) + quad) ^ sw) << 3;   // swizzled ushort offset
            v8s af[4], bf[4];
            #pragma unroll
            for (int t = 0; t < 4; t++) {
                af[t] = *(const v8s*)(Al + (wr * 64 + t * 16 + col) * 64 + ko);
                bf[t] = *(const v8s*)(Bl + (wc * 64 + t * 16 + col) * 64 + ko);
            }
            #pragma unroll
            for (int tr = 0; tr < 4; tr++)
                #pragma unroll
                for (int tc = 0; tc < 4; tc++)
                    acc[tr][tc] = __builtin_amdgcn_mfma_f32_16x16x32_bf16(
                        af[tr], bf[tc], acc[tr][tc], 0, 0, 0);
        }
    }
}

#define ZERO_ACC(a) { _Pragma("unroll") for (int _i = 0; _i < 4; _i++) \
    _Pragma("unroll") for (int _j = 0; _j < 4; _j++) a[_i][_j] = (v4f){0.f,0.f,0.f,0.f}; }

// ---------------------------------------------------------------------------
// Kernel 2: fz = z @ W^T + b for BOTH weights in one launch.
// grid (32, 4): y<2 -> f1 (cols y*128), y>=2 -> f2.
// ---------------------------------------------------------------------------
__global__ __launch_bounds__(256, 2) void fz_gemm(
    const unsigned short* __restrict__ zb,
    const unsigned short* __restrict__ w1b, const unsigned short* __restrict__ w2b,
    const float* __restrict__ b1, const float* __restrict__ b2,
    unsigned short* __restrict__ f1z, unsigned short* __restrict__ f2z)
{
    __shared__ __align__(16) unsigned short Al[128 * 64];
    __shared__ __align__(16) unsigned short Bl[128 * 64];
    int which = blockIdx.y >> 1;
    const unsigned short* wb = which ? w2b : w1b;
    const float* bias = which ? b2 : b1;
    unsigned short* outz = which ? f2z : f1z;
    int mBase = blockIdx.x * 128, nBase = (blockIdx.y & 1) * 128;
    v4f acc[4][4]; ZERO_ACC(acc);
    mm_tile128(zb, wb, mBase, nBase, D_N, Al, Bl, acc);
    int tid = threadIdx.x, lane = tid & 63, wave = tid >> 6, quad = lane >> 4, col = lane & 15;
    int wr = wave >> 1, wc = wave & 1;
    #pragma unroll
    for (int tr = 0; tr < 4; tr++)
        #pragma unroll
        for (int tc = 0; tc < 4; tc++) {
            int gcol = nBase + wc * 64 + tc * 16 + col;
            float bv = bias[gcol];
            #pragma unroll
            for (int reg = 0; reg < 4; reg++) {
                int grow = mBase + wr * 64 + tr * 16 + quad * 4 + reg;
                outz[(size_t)grow * HID_N + gcol] = f2bf(acc[tr][tc][reg] + bv);
            }
        }
}

// ---------------------------------------------------------------------------
// Kernel 3: per-row softmax over gathered logits. Wave-per-4-rows,
// shuffle-only reductions. grid 256 blocks x 16 rows.
// ---------------------------------------------------------------------------
__global__ __launch_bounds__(256) void softmax_mean(
    const float* __restrict__ logits, const int* __restrict__ oldi,
    const int* __restrict__ newi, float* __restrict__ msums)
{
    __shared__ int act[256];
    __shared__ float accs[4][256];
    int tid = threadIdx.x, lane = tid & 63, wave = tid >> 6;
    if (tid < NCLS) act[tid] = (tid < 100) ? oldi[tid] : newi[tid - 100];
    accs[0][tid] = 0.f; accs[1][tid] = 0.f; accs[2][tid] = 0.f; accs[3][tid] = 0.f;
    __syncthreads();
    int a0 = act[lane], a1 = act[lane + 64], a2 = act[lane + 128];
    int a3 = (lane < 8) ? act[lane + 192] : 0;
    int r0 = blockIdx.x * 16 + wave * 4;
    float c0 = 0.f, c1 = 0.f, c2 = 0.f, c3 = 0.f;
    for (int i = 0; i < 4; i++) {
        const float* lr = logits + (size_t)(r0 + i) * NCLS;
        float x0 = lr[a0], x1 = lr[a1], x2 = lr[a2];
        float x3 = (lane < 8) ? lr[a3] : -3.0e38f;
        float m = fmaxf(fmaxf(x0, x1), fmaxf(x2, x3));
        #pragma unroll
        for (int s = 32; s > 0; s >>= 1) m = fmaxf(m, __shfl_xor(m, s));
        float e0 = __expf(x0 - m), e1 = __expf(x1 - m), e2 = __expf(x2 - m);
        float e3 = (lane < 8) ? __expf(x3 - m) : 0.f;
        float sm = e0 + e1 + e2 + e3;
        #pragma unroll
        for (int s = 32; s > 0; s >>= 1) sm += __shfl_xor(sm, s);
        float inv = 1.0f / sm;
        c0 += e0 * inv; c1 += e1 * inv; c2 += e2 * inv; c3 += e3 * inv;
    }
    accs[wave][lane] = c0; accs[wave][lane + 64] = c1; accs[wave][lane + 128] = c2;
    if (lane < 8) accs[wave][lane + 192] = c3;
    __syncthreads();
    if (tid < NCLS)
        atomicAdd(&msums[tid], accs[0][tid] + accs[1][tid] + accs[2][tid] + accs[3][tid]);
}

// ---------------------------------------------------------------------------
// Kernel 4: fused contrastive main. grid (32, 32); block = 128x128 tile.
// Three sequential GEMMs over the same output tile; register economization:
// mask -> 64-bit mask, sim acc -> dsum[16] + bf16-packed sv, then attn acc.
// Two waves share each row (2x2 grid) so partials are [B][64][4]
// (chunk = jc*2 + wc).
// ---------------------------------------------------------------------------
__global__ __launch_bounds__(256, 2) void main_fused(
    const unsigned short* __restrict__ zn, const unsigned short* __restrict__ bn,
    const unsigned short* __restrict__ f1z, const unsigned short* __restrict__ f2z,
    float* __restrict__ partials)
{
    __shared__ __align__(16) unsigned short Al[128 * 64];
    __shared__ __align__(16) unsigned short Bl[128 * 64];
    int tid = threadIdx.x, lane = tid & 63, wave = tid >> 6, quad = lane >> 4, col = lane & 15;
    int wr = wave >> 1, wc = wave & 1;
    int ib = blockIdx.x, jc = blockIdx.y;
    int rBase = ib * 128 + wr * 64;
    int cBase = jc * 128 + wc * 64;

    v4f acc[4][4];

    // --- phase 1: base_sim -> 64-bit mask ---
    ZERO_ACC(acc);
    mm_tile128(bn, bn, ib * 128, jc * 128, D_N, Al, Bl, acc);
    unsigned long long mb = 0ull;
    #pragma unroll
    for (int tr = 0; tr < 4; tr++)
        #pragma unroll
        for (int tc = 0; tc < 4; tc++)
            #pragma unroll
            for (int reg = 0; reg < 4; reg++) {
                int grow = rBase + tr * 16 + quad * 4 + reg;
                int gcol = cBase + tc * 16 + col;
                if (acc[tr][tc][reg] > 0.05f && grow != gcol)
                    mb |= 1ull << (tr * 16 + tc * 4 + reg);
            }

    // --- phase 2: sim -> dsum[16] + packed bf16 sv ---
    ZERO_ACC(acc);
    mm_tile128(zn, zn, ib * 128, jc * 128, D_N, Al, Bl, acc);
    float dsum[16];
    #pragma unroll
    for (int i = 0; i < 16; i++) dsum[i] = 0.f;
    unsigned int svp[4][4][2];
    #pragma unroll
    for (int tr = 0; tr < 4; tr++)
        #pragma unroll
        for (int tc = 0; tc < 4; tc++) {
            #pragma unroll
            for (int reg = 0; reg < 4; reg++) {
                float sv = acc[tr][tc][reg];
                int grow = rBase + tr * 16 + quad * 4 + reg;
                int gcol = cBase + tc * 16 + col;
                if (grow != gcol) dsum[tr * 4 + reg] += __expf(sv * 10.0f);
            }
            svp[tr][tc][0] = ((unsigned int)f2bf(acc[tr][tc][1]) << 16) | f2bf(acc[tr][tc][0]);
            svp[tr][tc][1] = ((unsigned int)f2bf(acc[tr][tc][3]) << 16) | f2bf(acc[tr][tc][2]);
        }

    // --- phase 3: attn -> combine ---
    ZERO_ACC(acc);
    mm_tile128(f1z, f2z, ib * 128, jc * 128, HID_N, Al, Bl, acc);
    float lsum[16], asum[16], nnf[16];
    #pragma unroll
    for (int i = 0; i < 16; i++) { lsum[i] = 0.f; asum[i] = 0.f; nnf[i] = 0.f; }
    #pragma unroll
    for (int tr = 0; tr < 4; tr++)
        #pragma unroll
        for (int tc = 0; tc < 4; tc++)
            #pragma unroll
            for (int reg = 0; reg < 4; reg++) {
                if ((mb >> (tr * 16 + tc * 4 + reg)) & 1ull) {
                    int slot = tr * 4 + reg;
                    float e = __expf(acc[tr][tc][reg]);
                    unsigned int pk = svp[tr][tc][reg >> 1];
                    float sv = bf2f((unsigned short)((reg & 1) ? (pk >> 16) : (pk & 0xFFFF)));
                    lsum[slot] += e;
                    asum[slot] += e * sv;
                    nnf[slot] += 1.f;
                }
            }

    // merge the 16 column-lanes per row; lane col==0 stores partials
    #pragma unroll
    for (int i = 0; i < 16; i++) {
        #pragma unroll
        for (int m = 1; m < 16; m <<= 1) {
            lsum[i] += __shfl_xor(lsum[i], m);
            asum[i] += __shfl_xor(asum[i], m);
            dsum[i] += __shfl_xor(dsum[i], m);
            nnf[i]  += __shfl_xor(nnf[i], m);
        }
        if (col == 0) {
            int row = rBase + (i >> 2) * 16 + quad * 4 + (i & 3);
            float4 v; v.x = lsum[i]; v.y = asum[i]; v.z = dsum[i]; v.w = nnf[i];
            *(float4*)(partials + ((size_t)row * 64 + jc * 2 + wc) * 4) = v;
        }
    }
}

// ---------------------------------------------------------------------------
// Kernel 5: reduce per-row partials over 64 chunks; last block (device-scope
// atomic counter) computes entropy term + final combine -> d_out[0].
// ---------------------------------------------------------------------------
__global__ __launch_bounds__(256) void row_reduce_fin(
    const float* __restrict__ partials, const float* __restrict__ msums,
    float* __restrict__ acc, float* __restrict__ out)
{
    int tid = threadIdx.x;
    int r = blockIdx.x * 256 + tid;
    const float4* p = (const float4*)partials + (size_t)r * 64;
    float L = 0.f, A = 0.f, Dn = 0.f, NN = 0.f;
    #pragma unroll
    for (int c = 0; c < 64; c++) { float4 v = p[c]; L += v.x; A += v.y; Dn += v.z; NN += v.w; }
    float per = 0.f, val = 0.f;
    if (NN > 0.5f) {
        per = (logf(Dn + 1e-8f) - 10.0f * (A / L)) / NN;
        val = 1.0f;
    }
    __shared__ float red[256];
    __shared__ float r2s[256];
    __shared__ int amLast;
    red[tid] = per; r2s[tid] = val; __syncthreads();
    for (int s = 128; s > 0; s >>= 1) {
        if (tid < s) { red[tid] += red[tid + s]; r2s[tid] += r2s[tid + s]; }
        __syncthreads();
    }
    if (tid == 0) {
        atomicAdd(&acc[0], red[0]);
        atomicAdd(&acc[1], r2s[0]);
        __threadfence();
        int old = atomicAdd((int*)&acc[2], 1);
        amLast = (old == (int)gridDim.x - 1);
    }
    __syncthreads();
    if (!amLast) return;

    // ---- final block: entropy + combine ----
    __shared__ float bcast[2];
    float pcl = (tid < NCLS) ? msums[tid] * (1.0f / 4096.0f) : 0.0f;
    red[tid] = (tid < 100) ? pcl : 0.0f; __syncthreads();
    for (int s = 128; s > 0; s >>= 1) { if (tid < s) red[tid] += red[tid + s]; __syncthreads(); }
    if (tid == 0) bcast[0] = red[0];
    __syncthreads();
    red[tid] = (tid >= 100 && tid < NCLS) ? pcl : 0.0f; __syncthreads();
    for (int s = 128; s > 0; s >>= 1) { if (tid < s) red[tid] += red[tid + s]; __syncthreads(); }
    if (tid == 0) bcast[1] = red[0];
    __syncthreads();
    float p_old = bcast[0], p_new = bcast[1];

    float t = 0.0f;
    if (tid < 100)       { float q = pcl / (p_old + 1e-8f); t = q * logf(q + 1e-8f); }
    else if (tid < NCLS) { float q = pcl / (p_new + 1e-8f); t = q * logf(q + 1e-8f); }
    red[tid] = t; __syncthreads();
    for (int s = 128; s > 0; s >>= 1) { if (tid < s) red[tid] += red[tid + s]; __syncthreads(); }

    if (tid == 0) {
        float s0 = __hip_atomic_load(&acc[0], __ATOMIC_RELAXED, __HIP_MEMORY_SCOPE_AGENT);
        float s1 = __hip_atomic_load(&acc[1], __ATOMIC_RELAXED, __HIP_MEMORY_SCOPE_AGENT);
        float loss_inter = p_old * logf(p_old + 1e-8f) + p_new * logf(p_new + 1e-8f)
                           + 0.69314718056f;
        float loss_entropy = loss_inter + red[0] + 2.0f * 4.60517018599f;
        float lc = (s1 > 0.5f) ? s0 / s1 : 0.0f;
        out[0] = loss_entropy + lc;
    }
}

// ---------------------------------------------------------------------------
extern "C" void kernel_launch(void* const* d_in, const int* in_sizes, int n_in,
                              void* d_out, int out_size, void* d_ws, size_t ws_size,
                              hipStream_t stream)
{
    const float* z_u    = (const float*)d_in[0];
    const float* logits = (const float*)d_in[1];
    const int*   oldi   = (const int*)d_in[2];
    const int*   newi   = (const int*)d_in[3];
    const float* basef  = (const float*)d_in[4];
    const float* f1w    = (const float*)d_in[5];
    const float* f1b    = (const float*)d_in[6];
    const float* f2w    = (const float*)d_in[7];
    const float* f2b    = (const float*)d_in[8];
    float* out = (float*)d_out;

    unsigned short* zn   = (unsigned short*)d_ws;          // [B][D] bf16
    unsigned short* bn   = zn  + (size_t)B_N * D_N;
    unsigned short* zb   = bn  + (size_t)B_N * D_N;
    unsigned short* w1b  = zb  + (size_t)B_N * D_N;        // [HID][D]
    unsigned short* w2b  = w1b + (size_t)HID_N * D_N;
    unsigned short* f1z  = w2b + (size_t)HID_N * D_N;      // [B][HID]
    unsigned short* f2z  = f1z + (size_t)B_N * HID_N;
    float* partials = (float*)(f2z + (size_t)B_N * HID_N); // [B][64][4]
    float* msums    = partials + (size_t)B_N * 64 * 4;     // [200]
    float* accums   = msums + NCLS;                        // [2] + counter

    hipMemsetAsync(msums, 0, (NCLS + 8) * sizeof(float), stream);

    normalize_k<<<B_N + 8, 256, 0, stream>>>(z_u, basef, f1w, f2w, zn, bn, zb, w1b, w2b);
    fz_gemm<<<dim3(B_N / 128, 4), 256, 0, stream>>>(zb, w1b, w2b, f1b, f2b, f1z, f2z);
    softmax_mean<<<256, 256, 0, stream>>>(logits, oldi, newi, msums);
    main_fused<<<dim3(32, 32), 256, 0, stream>>>(zn, bn, f1z, f2z, partials);
    row_reduce_fin<<<B_N / 256, 256, 0, stream>>>(partials, msums, accums, out);
}

// Round 4
// 205.046 us; speedup vs baseline: 2.2652x; 1.0481x over previous
//
#include <hip/hip_runtime.h>

// ---------------------------------------------------------------------------
// Debiased Representation Loss — fused MI355X implementation (R4).
// Heavy part: three pairwise 4096x4096 matrices (mask K=768, sim K=768,
// attn K=256) fused flash-style. R4: mask+sim GEMMs fused into one K-loop
// (half the barriers), atomic-free softmax partials, 64-block row reduce.
// ---------------------------------------------------------------------------

#define B_N   4096
#define D_N   768
#define HID_N 256
#define NCLS  200

typedef __attribute__((ext_vector_type(8))) short v8s;   // 8 x bf16 (4 VGPRs)
typedef __attribute__((ext_vector_type(4))) float v4f;   // MFMA accumulator

// round-to-nearest-even fp32 -> bf16
__device__ __forceinline__ unsigned short f2bf(float x) {
    unsigned int u = __float_as_uint(x);
    unsigned int r = (u + 0x7FFFu + ((u >> 16) & 1u)) >> 16;
    return (unsigned short)r;
}
__device__ __forceinline__ float bf2f(unsigned short h) {
    return __uint_as_float((unsigned int)h << 16);
}

// async global->LDS, 16 B per lane; lane i lands at ldsbase + i*16
__device__ __forceinline__ void gld16(const unsigned short* g, unsigned short* l) {
    __builtin_amdgcn_global_load_lds(
        (__attribute__((address_space(1))) void*)g,
        (__attribute__((address_space(3))) void*)l, 16, 0, 0);
}

#define ZERO_ACC(a) { _Pragma("unroll") for (int _i = 0; _i < 4; _i++) \
    _Pragma("unroll") for (int _j = 0; _j < 4; _j++) a[_i][_j] = (v4f){0.f,0.f,0.f,0.f}; }

// ---------------------------------------------------------------------------
// Kernel 1: L2-normalize z_u and base_features rows; emit bf16 copies.
// Blocks >= 4096 convert f1_w / f2_w to bf16 instead.
// ---------------------------------------------------------------------------
__global__ __launch_bounds__(256) void normalize_k(
    const float* __restrict__ z, const float* __restrict__ base,
    const float* __restrict__ w1, const float* __restrict__ w2,
    unsigned short* __restrict__ zn, unsigned short* __restrict__ bn,
    unsigned short* __restrict__ zb,
    unsigned short* __restrict__ o1, unsigned short* __restrict__ o2)
{
    int tid = threadIdx.x;
    if (blockIdx.x >= B_N) {                     // weight conversion tail
        int b2 = blockIdx.x - B_N;               // 0..7
        const float* src = (b2 < 4) ? w1 : w2;
        unsigned short* dst = (b2 < 4) ? o1 : o2;
        int base2 = (b2 & 3) * 49152 + tid;      // 196608/4 per block
        #pragma unroll 4
        for (int i = 0; i < 192; i++) dst[base2 + i * 256] = f2bf(src[base2 + i * 256]);
        return;
    }
    int row = blockIdx.x;
    __shared__ float ws1[4], ws2[4];
    const float* zr = z    + (size_t)row * D_N;
    const float* br = base + (size_t)row * D_N;
    float z0 = zr[tid], z1 = zr[tid + 256], z2 = zr[tid + 512];
    float b0 = br[tid], b1 = br[tid + 256], b2 = br[tid + 512];
    float s1 = z0*z0 + z1*z1 + z2*z2;
    float s2 = b0*b0 + b1*b1 + b2*b2;
    #pragma unroll
    for (int m = 32; m > 0; m >>= 1) { s1 += __shfl_xor(s1, m); s2 += __shfl_xor(s2, m); }
    if ((tid & 63) == 0) { ws1[tid >> 6] = s1; ws2[tid >> 6] = s2; }
    __syncthreads();
    float t1 = ws1[0] + ws1[1] + ws1[2] + ws1[3];
    float t2 = ws2[0] + ws2[1] + ws2[2] + ws2[3];
    float sc1 = 1.0f / fmaxf(sqrtf(t1), 1e-12f);
    float sc2 = 1.0f / fmaxf(sqrtf(t2), 1e-12f);
    size_t o = (size_t)row * D_N;
    zn[o+tid] = f2bf(z0*sc1); zn[o+tid+256] = f2bf(z1*sc1); zn[o+tid+512] = f2bf(z2*sc1);
    bn[o+tid] = f2bf(b0*sc2); bn[o+tid+256] = f2bf(b1*sc2); bn[o+tid+512] = f2bf(b2*sc2);
    zb[o+tid] = f2bf(z0);     zb[o+tid+256] = f2bf(z1);     zb[o+tid+512] = f2bf(z2);
}

// ---------------------------------------------------------------------------
// Shared mini-GEMM: block tile 128x128, NT bf16; 2x2 wave grid, 4x4 MFMA
// tiles per wave. global_load_lds width-16 staging, XOR-swizzled unpadded
// LDS rows (stride 64 ushorts): physical kblock = logical ^ (row & 7).
// (0 bank conflicts measured in R2/R3.)  Used by fz_gemm only.
// ---------------------------------------------------------------------------
__device__ __forceinline__ void mm_tile128(
    const unsigned short* __restrict__ Ag, const unsigned short* __restrict__ Bg,
    int aRow0, int bRow0, int K,
    unsigned short* Al, unsigned short* Bl, v4f acc[4][4])
{
    const int tid = threadIdx.x;
    const int lane = tid & 63, wave = tid >> 6, quad = lane >> 4, col = lane & 15;
    const int wr = wave >> 1, wc = wave & 1;
    const int r8 = lane >> 3;
    const int kbl = (lane & 7) ^ r8;
    const int sw  = col & 7;
    for (int kc = 0; kc < K; kc += 64) {
        __syncthreads();
        #pragma unroll
        for (int s = 0; s < 4; s++) {
            int rowbase = s * 32 + wave * 8;
            gld16(Ag + (size_t)(aRow0 + rowbase + r8) * K + kc + kbl * 8,
                  Al + rowbase * 64);
            gld16(Bg + (size_t)(bRow0 + rowbase + r8) * K + kc + kbl * 8,
                  Bl + rowbase * 64);
        }
        __syncthreads();
        #pragma unroll
        for (int kk = 0; kk < 2; kk++) {
            int ko = (((kk << 2) + quad) ^ sw) << 3;
            v8s af[4], bf[4];
            #pragma unroll
            for (int t = 0; t < 4; t++) {
                af[t] = *(const v8s*)(Al + (wr * 64 + t * 16 + col) * 64 + ko);
                bf[t] = *(const v8s*)(Bl + (wc * 64 + t * 16 + col) * 64 + ko);
            }
            #pragma unroll
            for (int tr = 0; tr < 4; tr++)
                #pragma unroll
                for (int tc = 0; tc < 4; tc++)
                    acc[tr][tc] = __builtin_amdgcn_mfma_f32_16x16x32_bf16(
                        af[tr], bf[tc], acc[tr][tc], 0, 0, 0);
        }
    }
}

// ---------------------------------------------------------------------------
// Kernel 2: fz = z @ W^T + b for BOTH weights in one launch. grid (32, 4).
// ---------------------------------------------------------------------------
__global__ __launch_bounds__(256, 2) void fz_gemm(
    const unsigned short* __restrict__ zb,
    const unsigned short* __restrict__ w1b, const unsigned short* __restrict__ w2b,
    const float* __restrict__ b1, const float* __restrict__ b2,
    unsigned short* __restrict__ f1z, unsigned short* __restrict__ f2z)
{
    __shared__ __align__(16) unsigned short Al[128 * 64];
    __shared__ __align__(16) unsigned short Bl[128 * 64];
    int which = blockIdx.y >> 1;
    const unsigned short* wb = which ? w2b : w1b;
    const float* bias = which ? b2 : b1;
    unsigned short* outz = which ? f2z : f1z;
    int mBase = blockIdx.x * 128, nBase = (blockIdx.y & 1) * 128;
    v4f acc[4][4]; ZERO_ACC(acc);
    mm_tile128(zb, wb, mBase, nBase, D_N, Al, Bl, acc);
    int tid = threadIdx.x, lane = tid & 63, wave = tid >> 6, quad = lane >> 4, col = lane & 15;
    int wr = wave >> 1, wc = wave & 1;
    #pragma unroll
    for (int tr = 0; tr < 4; tr++)
        #pragma unroll
        for (int tc = 0; tc < 4; tc++) {
            int gcol = nBase + wc * 64 + tc * 16 + col;
            float bv = bias[gcol];
            #pragma unroll
            for (int reg = 0; reg < 4; reg++) {
                int grow = mBase + wr * 64 + tr * 16 + quad * 4 + reg;
                outz[(size_t)grow * HID_N + gcol] = f2bf(acc[tr][tc][reg] + bv);
            }
        }
}

// ---------------------------------------------------------------------------
// Kernel 3: per-row softmax over gathered logits; ATOMIC-FREE: each block
// writes its per-class partial sum to mpart[class*256 + block].
// grid 256 blocks x 16 rows.
// ---------------------------------------------------------------------------
__global__ __launch_bounds__(256) void softmax_mean(
    const float* __restrict__ logits, const int* __restrict__ oldi,
    const int* __restrict__ newi, float* __restrict__ mpart)
{
    __shared__ int act[256];
    __shared__ float accs[4][256];
    int tid = threadIdx.x, lane = tid & 63, wave = tid >> 6;
    if (tid < NCLS) act[tid] = (tid < 100) ? oldi[tid] : newi[tid - 100];
    accs[0][tid] = 0.f; accs[1][tid] = 0.f; accs[2][tid] = 0.f; accs[3][tid] = 0.f;
    __syncthreads();
    int a0 = act[lane], a1 = act[lane + 64], a2 = act[lane + 128];
    int a3 = (lane < 8) ? act[lane + 192] : 0;
    int r0 = blockIdx.x * 16 + wave * 4;
    float c0 = 0.f, c1 = 0.f, c2 = 0.f, c3 = 0.f;
    for (int i = 0; i < 4; i++) {
        const float* lr = logits + (size_t)(r0 + i) * NCLS;
        float x0 = lr[a0], x1 = lr[a1], x2 = lr[a2];
        float x3 = (lane < 8) ? lr[a3] : -3.0e38f;
        float m = fmaxf(fmaxf(x0, x1), fmaxf(x2, x3));
        #pragma unroll
        for (int s = 32; s > 0; s >>= 1) m = fmaxf(m, __shfl_xor(m, s));
        float e0 = __expf(x0 - m), e1 = __expf(x1 - m), e2 = __expf(x2 - m);
        float e3 = (lane < 8) ? __expf(x3 - m) : 0.f;
        float sm = e0 + e1 + e2 + e3;
        #pragma unroll
        for (int s = 32; s > 0; s >>= 1) sm += __shfl_xor(sm, s);
        float inv = 1.0f / sm;
        c0 += e0 * inv; c1 += e1 * inv; c2 += e2 * inv; c3 += e3 * inv;
    }
    accs[wave][lane] = c0; accs[wave][lane + 64] = c1; accs[wave][lane + 128] = c2;
    if (lane < 8) accs[wave][lane + 192] = c3;
    __syncthreads();
    mpart[(size_t)tid * 256 + blockIdx.x] =
        accs[0][tid] + accs[1][tid] + accs[2][tid] + accs[3][tid];
}

// ---------------------------------------------------------------------------
// Kernel 4: fused contrastive main. grid (32, 32); block = 128x128 tile.
// R4: mask (bn.bn^T) and sim (zn.zn^T) GEMMs share ONE K=768 loop with 4 LDS
// buffers -> half the barriers for 2/3 of the FLOPs; attn phase (K=256) does
// 128-K per barrier-pair. 2x2 wave grid; partial chunk = jc*2 + wc.
// ---------------------------------------------------------------------------
__global__ __launch_bounds__(256, 2) void main_fused(
    const unsigned short* __restrict__ zn, const unsigned short* __restrict__ bn,
    const unsigned short* __restrict__ f1z, const unsigned short* __restrict__ f2z,
    float* __restrict__ partials)
{
    __shared__ __align__(16) unsigned short A1[128 * 64];
    __shared__ __align__(16) unsigned short B1[128 * 64];
    __shared__ __align__(16) unsigned short A2[128 * 64];
    __shared__ __align__(16) unsigned short B2[128 * 64];
    int tid = threadIdx.x, lane = tid & 63, wave = tid >> 6, quad = lane >> 4, col = lane & 15;
    int wr = wave >> 1, wc = wave & 1;
    int ib = blockIdx.x, jc = blockIdx.y;
    int rBase = ib * 128 + wr * 64;
    int cBase = jc * 128 + wc * 64;
    const int r8 = lane >> 3;
    const int kbl = (lane & 7) ^ r8;
    const int sw  = col & 7;

    // --- fused phase 1+2: mask GEMM (accB) + sim GEMM (accS), K = 768 ---
    v4f accB[4][4], accS[4][4];
    ZERO_ACC(accB); ZERO_ACC(accS);
    for (int kc = 0; kc < D_N; kc += 64) {
        __syncthreads();
        #pragma unroll
        for (int s = 0; s < 4; s++) {
            int rowbase = s * 32 + wave * 8;
            size_t rOff = (size_t)(ib * 128 + rowbase + r8) * D_N + kc + kbl * 8;
            size_t cOff = (size_t)(jc * 128 + rowbase + r8) * D_N + kc + kbl * 8;
            gld16(bn + rOff, A1 + rowbase * 64);
            gld16(bn + cOff, B1 + rowbase * 64);
            gld16(zn + rOff, A2 + rowbase * 64);
            gld16(zn + cOff, B2 + rowbase * 64);
        }
        __syncthreads();
        #pragma unroll
        for (int kk = 0; kk < 2; kk++) {
            int ko = (((kk << 2) + quad) ^ sw) << 3;
            v8s a1[4], b1[4], a2[4], b2[4];
            #pragma unroll
            for (int t = 0; t < 4; t++) {
                a1[t] = *(const v8s*)(A1 + (wr * 64 + t * 16 + col) * 64 + ko);
                b1[t] = *(const v8s*)(B1 + (wc * 64 + t * 16 + col) * 64 + ko);
                a2[t] = *(const v8s*)(A2 + (wr * 64 + t * 16 + col) * 64 + ko);
                b2[t] = *(const v8s*)(B2 + (wc * 64 + t * 16 + col) * 64 + ko);
            }
            #pragma unroll
            for (int tr = 0; tr < 4; tr++)
                #pragma unroll
                for (int tc = 0; tc < 4; tc++) {
                    accB[tr][tc] = __builtin_amdgcn_mfma_f32_16x16x32_bf16(
                        a1[tr], b1[tc], accB[tr][tc], 0, 0, 0);
                    accS[tr][tc] = __builtin_amdgcn_mfma_f32_16x16x32_bf16(
                        a2[tr], b2[tc], accS[tr][tc], 0, 0, 0);
                }
        }
    }

    // mask bits from accB
    unsigned long long mb = 0ull;
    #pragma unroll
    for (int tr = 0; tr < 4; tr++)
        #pragma unroll
        for (int tc = 0; tc < 4; tc++)
            #pragma unroll
            for (int reg = 0; reg < 4; reg++) {
                int grow = rBase + tr * 16 + quad * 4 + reg;
                int gcol = cBase + tc * 16 + col;
                if (accB[tr][tc][reg] > 0.05f && grow != gcol)
                    mb |= 1ull << (tr * 16 + tc * 4 + reg);
            }

    // dsum + packed bf16 sim values from accS
    float dsum[16];
    #pragma unroll
    for (int i = 0; i < 16; i++) dsum[i] = 0.f;
    unsigned int svp[4][4][2];
    #pragma unroll
    for (int tr = 0; tr < 4; tr++)
        #pragma unroll
        for (int tc = 0; tc < 4; tc++) {
            #pragma unroll
            for (int reg = 0; reg < 4; reg++) {
                float sv = accS[tr][tc][reg];
                int grow = rBase + tr * 16 + quad * 4 + reg;
                int gcol = cBase + tc * 16 + col;
                if (grow != gcol) dsum[tr * 4 + reg] += __expf(sv * 10.0f);
            }
            svp[tr][tc][0] = ((unsigned int)f2bf(accS[tr][tc][1]) << 16) | f2bf(accS[tr][tc][0]);
            svp[tr][tc][1] = ((unsigned int)f2bf(accS[tr][tc][3]) << 16) | f2bf(accS[tr][tc][2]);
        }

    // --- phase 3: attn GEMM (K=256), 128-K per barrier-pair ---
    v4f accA[4][4]; ZERO_ACC(accA);
    for (int kc = 0; kc < HID_N; kc += 128) {
        __syncthreads();
        #pragma unroll
        for (int s = 0; s < 4; s++) {
            int rowbase = s * 32 + wave * 8;
            size_t rOff = (size_t)(ib * 128 + rowbase + r8) * HID_N + kc + kbl * 8;
            size_t cOff = (size_t)(jc * 128 + rowbase + r8) * HID_N + kc + kbl * 8;
            gld16(f1z + rOff,      A1 + rowbase * 64);
            gld16(f2z + cOff,      B1 + rowbase * 64);
            gld16(f1z + rOff + 64, A2 + rowbase * 64);
            gld16(f2z + cOff + 64, B2 + rowbase * 64);
        }
        __syncthreads();
        #pragma unroll
        for (int half = 0; half < 2; half++) {
            const unsigned short* Ax = half ? A2 : A1;
            const unsigned short* Bx = half ? B2 : B1;
            #pragma unroll
            for (int kk = 0; kk < 2; kk++) {
                int ko = (((kk << 2) + quad) ^ sw) << 3;
                v8s af[4], bf[4];
                #pragma unroll
                for (int t = 0; t < 4; t++) {
                    af[t] = *(const v8s*)(Ax + (wr * 64 + t * 16 + col) * 64 + ko);
                    bf[t] = *(const v8s*)(Bx + (wc * 64 + t * 16 + col) * 64 + ko);
                }
                #pragma unroll
                for (int tr = 0; tr < 4; tr++)
                    #pragma unroll
                    for (int tc = 0; tc < 4; tc++)
                        accA[tr][tc] = __builtin_amdgcn_mfma_f32_16x16x32_bf16(
                            af[tr], bf[tc], accA[tr][tc], 0, 0, 0);
            }
        }
    }

    // --- combine ---
    float lsum[16], asum[16], nnf[16];
    #pragma unroll
    for (int i = 0; i < 16; i++) { lsum[i] = 0.f; asum[i] = 0.f; nnf[i] = 0.f; }
    #pragma unroll
    for (int tr = 0; tr < 4; tr++)
        #pragma unroll
        for (int tc = 0; tc < 4; tc++)
            #pragma unroll
            for (int reg = 0; reg < 4; reg++) {
                if ((mb >> (tr * 16 + tc * 4 + reg)) & 1ull) {
                    int slot = tr * 4 + reg;
                    float e = __expf(accA[tr][tc][reg]);
                    unsigned int pk = svp[tr][tc][reg >> 1];
                    float sv = bf2f((unsigned short)((reg & 1) ? (pk >> 16) : (pk & 0xFFFF)));
                    lsum[slot] += e;
                    asum[slot] += e * sv;
                    nnf[slot] += 1.f;
                }
            }

    #pragma unroll
    for (int i = 0; i < 16; i++) {
        #pragma unroll
        for (int m = 1; m < 16; m <<= 1) {
            lsum[i] += __shfl_xor(lsum[i], m);
            asum[i] += __shfl_xor(asum[i], m);
            dsum[i] += __shfl_xor(dsum[i], m);
            nnf[i]  += __shfl_xor(nnf[i], m);
        }
        if (col == 0) {
            int row = rBase + (i >> 2) * 16 + quad * 4 + (i & 3);
            float4 v; v.x = lsum[i]; v.y = asum[i]; v.z = dsum[i]; v.w = nnf[i];
            *(float4*)(partials + ((size_t)row * 64 + jc * 2 + wc) * 4) = v;
        }
    }
}

// ---------------------------------------------------------------------------
// Kernel 5: reduce per-row partials (64 blocks, 4 lanes/row); last block
// computes entropy term from mpart + final combine -> d_out[0].
// ---------------------------------------------------------------------------
__global__ __launch_bounds__(256) void row_reduce_fin(
    const float* __restrict__ partials, const float* __restrict__ mpart,
    float* __restrict__ acc, float* __restrict__ out)
{
    int tid = threadIdx.x;
    int row = blockIdx.x * 64 + (tid >> 2);
    int sub = tid & 3;
    const float4* p = (const float4*)partials + (size_t)row * 64 + sub * 16;
    float L = 0.f, A = 0.f, Dn = 0.f, NN = 0.f;
    #pragma unroll
    for (int c = 0; c < 16; c++) { float4 v = p[c]; L += v.x; A += v.y; Dn += v.z; NN += v.w; }
    #pragma unroll
    for (int m = 1; m < 4; m <<= 1) {
        L += __shfl_xor(L, m); A += __shfl_xor(A, m);
        Dn += __shfl_xor(Dn, m); NN += __shfl_xor(NN, m);
    }
    float per = 0.f, val = 0.f;
    if (sub == 0 && NN > 0.5f) {
        per = (logf(Dn + 1e-8f) - 10.0f * (A / L)) / NN;
        val = 1.0f;
    }
    __shared__ float red[256];
    __shared__ float r2s[256];
    __shared__ int amLast;
    red[tid] = per; r2s[tid] = val; __syncthreads();
    for (int s = 128; s > 0; s >>= 1) {
        if (tid < s) { red[tid] += red[tid + s]; r2s[tid] += r2s[tid + s]; }
        __syncthreads();
    }
    if (tid == 0) {
        atomicAdd(&acc[0], red[0]);
        atomicAdd(&acc[1], r2s[0]);
        __threadfence();
        int old = atomicAdd((int*)&acc[2], 1);
        amLast = (old == (int)gridDim.x - 1);
    }
    __syncthreads();
    if (!amLast) return;

    // ---- final block: entropy + combine ----
    __shared__ float bcast[2];
    float pcl = 0.0f;
    if (tid < NCLS) {
        const float4* mp = (const float4*)(mpart + (size_t)tid * 256);
        float s = 0.f;
        #pragma unroll
        for (int c = 0; c < 64; c++) { float4 v = mp[c]; s += v.x + v.y + v.z + v.w; }
        pcl = s * (1.0f / 4096.0f);
    }
    red[tid] = (tid < 100) ? pcl : 0.0f; __syncthreads();
    for (int s = 128; s > 0; s >>= 1) { if (tid < s) red[tid] += red[tid + s]; __syncthreads(); }
    if (tid == 0) bcast[0] = red[0];
    __syncthreads();
    red[tid] = (tid >= 100 && tid < NCLS) ? pcl : 0.0f; __syncthreads();
    for (int s = 128; s > 0; s >>= 1) { if (tid < s) red[tid] += red[tid + s]; __syncthreads(); }
    if (tid == 0) bcast[1] = red[0];
    __syncthreads();
    float p_old = bcast[0], p_new = bcast[1];

    float t = 0.0f;
    if (tid < 100)       { float q = pcl / (p_old + 1e-8f); t = q * logf(q + 1e-8f); }
    else if (tid < NCLS) { float q = pcl / (p_new + 1e-8f); t = q * logf(q + 1e-8f); }
    red[tid] = t; __syncthreads();
    for (int s = 128; s > 0; s >>= 1) { if (tid < s) red[tid] += red[tid + s]; __syncthreads(); }

    if (tid == 0) {
        float s0 = __hip_atomic_load(&acc[0], __ATOMIC_RELAXED, __HIP_MEMORY_SCOPE_AGENT);
        float s1 = __hip_atomic_load(&acc[1], __ATOMIC_RELAXED, __HIP_MEMORY_SCOPE_AGENT);
        float loss_inter = p_old * logf(p_old + 1e-8f) + p_new * logf(p_new + 1e-8f)
                           + 0.69314718056f;
        float loss_entropy = loss_inter + red[0] + 2.0f * 4.60517018599f;
        float lc = (s1 > 0.5f) ? s0 / s1 : 0.0f;
        out[0] = loss_entropy + lc;
    }
}

// ---------------------------------------------------------------------------
extern "C" void kernel_launch(void* const* d_in, const int* in_sizes, int n_in,
                              void* d_out, int out_size, void* d_ws, size_t ws_size,
                              hipStream_t stream)
{
    const float* z_u    = (const float*)d_in[0];
    const float* logits = (const float*)d_in[1];
    const int*   oldi   = (const int*)d_in[2];
    const int*   newi   = (const int*)d_in[3];
    const float* basef  = (const float*)d_in[4];
    const float* f1w    = (const float*)d_in[5];
    const float* f1b    = (const float*)d_in[6];
    const float* f2w    = (const float*)d_in[7];
    const float* f2b    = (const float*)d_in[8];
    float* out = (float*)d_out;

    unsigned short* zn   = (unsigned short*)d_ws;          // [B][D] bf16
    unsigned short* bn   = zn  + (size_t)B_N * D_N;
    unsigned short* zb   = bn  + (size_t)B_N * D_N;
    unsigned short* w1b  = zb  + (size_t)B_N * D_N;        // [HID][D]
    unsigned short* w2b  = w1b + (size_t)HID_N * D_N;
    unsigned short* f1z  = w2b + (size_t)HID_N * D_N;      // [B][HID]
    unsigned short* f2z  = f1z + (size_t)B_N * HID_N;
    float* partials = (float*)(f2z + (size_t)B_N * HID_N); // [B][64][4]
    float* mpart    = partials + (size_t)B_N * 64 * 4;     // [256 class][256 blk]
    float* accums   = mpart + 256 * 256;                   // [2] + counter

    hipMemsetAsync(accums, 0, 4 * sizeof(float), stream);

    normalize_k<<<B_N + 8, 256, 0, stream>>>(z_u, basef, f1w, f2w, zn, bn, zb, w1b, w2b);
    fz_gemm<<<dim3(B_N / 128, 4), 256, 0, stream>>>(zb, w1b, w2b, f1b, f2b, f1z, f2z);
    softmax_mean<<<256, 256, 0, stream>>>(logits, oldi, newi, mpart);
    main_fused<<<dim3(32, 32), 256, 0, stream>>>(zn, bn, f1z, f2z, partials);
    row_reduce_fin<<<64, 256, 0, stream>>>(partials, mpart, accums, out);
}